// Round 1
// baseline (68.298 us; speedup 1.0000x reference)
//
#include <hip/hip_runtime.h>

typedef __attribute__((ext_vector_type(8))) short short8;
typedef __attribute__((ext_vector_type(4))) float f32x4;

#define CI    128
#define CO_   256
#define HW_   56
#define PLANE 3136
#define NB    16
#define STOT  50176
#define KTOT  1152
#define OUTN  802816   // CO_*PLANE

// ws layout: [0, 12845056) Xt bf16 NHWC ; [12845056, +589824) Wpre bf16 (LDS-image order) ; then 256B zeros
#define XT_BYTES   12845056ull
#define WP_USHORTS 294912
#define WS_NEED    (12845056ull + 589824ull + 256ull)

__device__ __forceinline__ unsigned short f2bf(float f) {
  unsigned u = __float_as_uint(f);
  u += 0x7FFFu + ((u >> 16) & 1u);   // RNE
  return (unsigned short)(u >> 16);
}

__device__ __forceinline__ void gload16(void* lds, const void* g) {
  __builtin_amdgcn_global_load_lds(
      (const __attribute__((address_space(1))) unsigned int*)g,
      (__attribute__((address_space(3))) unsigned int*)lds, 16, 0, 0);
}

// ---------------- prep_x: NCHW fp32 -> NHWC bf16 (tiled transpose) ----------------
// grid: 16 n * 4 ci-blocks * 25 sp-blocks(128) = 1600 blocks, 256 thr
__global__ __launch_bounds__(256) void prep_x(const float* __restrict__ X,
                                              unsigned short* __restrict__ Xt) {
  __shared__ __align__(16) unsigned short tile[32][132];
  const int t = threadIdx.x;
  const int bx = blockIdx.x;
  const int n   = bx / 100;
  const int rem = bx % 100;
  const int cib = rem / 25;
  const int spb = rem % 25;
  const int sp0 = spb * 128;
  const float* src = X + (size_t)(n * CI + cib * 32) * PLANE;
#pragma unroll
  for (int j = 0; j < 4; ++j) {
    int f = t + 256 * j;            // 0..1023
    int ci  = f >> 5;               // 0..31
    int sp4 = (f & 31) * 4;         // 0..124
    if (sp0 + sp4 < PLANE) {
      f32x4 v = *(const f32x4*)(src + (size_t)ci * PLANE + sp0 + sp4);
#pragma unroll
      for (int e = 0; e < 4; ++e) tile[ci][sp4 + e] = f2bf(v[e]);
    }
  }
  __syncthreads();
  unsigned short* dst = Xt + ((size_t)n * PLANE + sp0) * CI + cib * 32;
#pragma unroll
  for (int j = 0; j < 2; ++j) {
    int g = t + 256 * j;            // 0..511
    int sp = g >> 2;                // 0..127
    int q  = g & 3;                 // 0..3 (8-ci chunk)
    if (sp0 + sp < PLANE) {
      short8 v;
#pragma unroll
      for (int e = 0; e < 8; ++e) v[e] = (short)tile[q * 8 + e][sp];
      *(short8*)(dst + (size_t)sp * CI + q * 8) = v;
    }
  }
}

// ---------------- prep_w: OIHW fp32 -> Wpre bf16 in LDS-image (pre-swizzled) order ----------------
// Wpre position p within an 8KB (r,cb,mt) block: co=p>>2, kg=(p&3)^(co&3), data = W[co][cb*32+kg*8+e][r]
// grid: 144 blocks * 256 = 36864 threads, 8 elems each
__global__ __launch_bounds__(256) void prep_w(const float* __restrict__ W,
                                              unsigned short* __restrict__ Wp) {
  const int u = blockIdx.x * 256 + threadIdx.x;  // 0..36863
  const int rcbmt = u >> 9;          // 0..71 = ((r*4+cb)*2+mt)
  const int p     = u & 511;
  const int mt  = rcbmt & 1;
  const int rcb = rcbmt >> 1;        // 0..35
  const int cb  = rcb & 3;
  const int r   = rcb >> 2;          // 0..8
  const int col = p >> 2;            // co_local 0..127
  const int kg  = (p & 3) ^ (col & 3);
  const int co  = mt * 128 + col;
  const int ci0 = cb * 32 + kg * 8;
  short8 v;
#pragma unroll
  for (int e = 0; e < 8; ++e)
    v[e] = (short)f2bf(W[(size_t)co * KTOT + (size_t)(ci0 + e) * 9 + r]);
  *(short8*)(Wp + (size_t)u * 8) = v;
  if (u < 16) {                       // 256B zeros region right after Wpre
    short8 z = {0, 0, 0, 0, 0, 0, 0, 0};
    *(short8*)(Wp + WP_USHORTS + u * 8) = z;
  }
}

// ---------------- conv_gemm: implicit GEMM, bf16 MFMA ----------------
// grid 784 = 2 co-tiles * 392 sp-tiles ; block 256 = 4 waves (2x2), each wave 64x64 out
__global__ __launch_bounds__(256) void conv_gemm(const unsigned short* __restrict__ Xt,
                                                 const unsigned short* __restrict__ Wp,
                                                 const float* __restrict__ bias,
                                                 float* __restrict__ out) {
  __shared__ __align__(1024) char smem[16384];  // A [0,8192), B [8192,16384)
  const int t    = threadIdx.x;
  const int lane = t & 63;
  const int wid  = t >> 6;
  const int wm   = wid >> 1, wn = wid & 1;

  int bx = blockIdx.x;
  bx = (bx & 7) * 98 + (bx >> 3);     // XCD swizzle, bijective (784 = 8*98)
  const int mt  = bx & 1;
  const int spt = bx >> 1;

  // --- staging thread roles (B side): thread t covers LDS chunks p=t (q=0) and p=256+t (q=1)
  const int kg = (t & 3) ^ ((t >> 2) & 3);
  const int S0 = spt * 128 + (t >> 2);
  const int S1 = S0 + 64;
  const int n0 = S0 / PLANE, hw0 = S0 - n0 * PLANE, h0 = hw0 / HW_, w0 = hw0 - h0 * HW_;
  const int n1 = S1 / PLANE, hw1 = S1 - n1 * PLANE, h1 = hw1 / HW_, w1 = hw1 - h1 * HW_;
  (void)n0; (void)n1;

  const char* xbase  = (const char*)Xt;
  const char* zbuf   = (const char*)(Wp + WP_USHORTS) + kg * 16;
  const char* wpbase = (const char*)Wp + mt * 8192 + t * 16;

  char* ldsA0 = smem + wid * 1024;
  char* ldsA1 = smem + 4096 + wid * 1024;
  char* ldsB0 = smem + 8192 + wid * 1024;
  char* ldsB1 = smem + 12288 + wid * 1024;

  // fragment read bases (swizzle folded in; lane-constant)
  const int swz  = ((lane >> 4) ^ (lane & 3)) * 16;
  const int aoff = (wm * 64 + (lane & 15)) * 64 + swz;
  const int boff = 8192 + (wn * 64 + (lane & 15)) * 64 + swz;

  f32x4 acc[4][4];
  const f32x4 zf = {0.f, 0.f, 0.f, 0.f};
#pragma unroll
  for (int m = 0; m < 4; ++m)
#pragma unroll
    for (int n = 0; n < 4; ++n) acc[m][n] = zf;

  for (int r = 0; r < 9; ++r) {
    const int dh = r / 3 - 1, dw = r % 3 - 1;
    const bool v0 = ((unsigned)(h0 + dh) < HW_) & ((unsigned)(w0 + dw) < HW_);
    const bool v1 = ((unsigned)(h1 + dh) < HW_) & ((unsigned)(w1 + dw) < HW_);
    const char* bs0 = v0 ? xbase + ((size_t)(S0 + dh * HW_ + dw) * CI + kg * 8) * 2 : zbuf;
    const char* bs1 = v1 ? xbase + ((size_t)(S1 + dh * HW_ + dw) * CI + kg * 8) * 2 : zbuf;
    const char* as_r = wpbase + r * 65536;   // + cb*16384 inner
#pragma unroll
    for (int cb = 0; cb < 4; ++cb) {
      const char* as = as_r + cb * 16384;
      gload16(ldsA0, as);
      gload16(ldsA1, as + 4096);
      gload16(ldsB0, bs0 + cb * 64);
      gload16(ldsB1, bs1 + cb * 64);
      __syncthreads();   // drains vmcnt -> staged data visible
      short8 a[4], b[4];
#pragma unroll
      for (int m = 0; m < 4; ++m) a[m] = *(const short8*)(smem + aoff + m * 1024);
#pragma unroll
      for (int n = 0; n < 4; ++n) b[n] = *(const short8*)(smem + boff + n * 1024);
#pragma unroll
      for (int m = 0; m < 4; ++m)
#pragma unroll
        for (int n = 0; n < 4; ++n)
          acc[m][n] = __builtin_amdgcn_mfma_f32_16x16x32_bf16(a[m], b[n], acc[m][n], 0, 0, 0);
      __syncthreads();   // protect LDS before next stage
    }
  }

  // ---- epilogue: D row = co = (lane>>4)*4+reg, col = sp = lane&15
  float bv[4][4];
#pragma unroll
  for (int mf = 0; mf < 4; ++mf) {
    int cobase = mt * 128 + wm * 64 + mf * 16 + (lane >> 4) * 4;
#pragma unroll
    for (int r2 = 0; r2 < 4; ++r2) bv[mf][r2] = bias[cobase + r2];
  }
#pragma unroll
  for (int nf = 0; nf < 4; ++nf) {
    int S = spt * 128 + wn * 64 + nf * 16 + (lane & 15);
    int n = S / PLANE, hw = S - n * PLANE;
    float* ob = out + (size_t)n * OUTN + hw;
#pragma unroll
    for (int mf = 0; mf < 4; ++mf) {
      int cobase = mt * 128 + wm * 64 + mf * 16 + (lane >> 4) * 4;
#pragma unroll
      for (int r2 = 0; r2 < 4; ++r2)
        ob[(size_t)(cobase + r2) * PLANE] = acc[mf][nf][r2] + bv[mf][r2];
    }
  }
}

// ---------------- fallback: naive direct conv (only if ws too small) ----------------
__global__ __launch_bounds__(256) void conv_naive(const float* __restrict__ X,
                                                  const float* __restrict__ W,
                                                  const float* __restrict__ bias,
                                                  float* __restrict__ out) {
  int idx = blockIdx.x * 256 + threadIdx.x;
  int hw = idx % PLANE;
  int co = (idx / PLANE) & 255;
  int n  = idx / (PLANE * 256);
  int h = hw / HW_, w = hw - h * HW_;
  float acc = bias[co];
  const float* xp = X + (size_t)n * CI * PLANE;
  const float* wp = W + (size_t)co * KTOT;
  for (int ci = 0; ci < CI; ++ci) {
#pragma unroll
    for (int kh = 0; kh < 3; ++kh) {
      int y = h + kh - 1;
      if ((unsigned)y >= HW_) continue;
#pragma unroll
      for (int kw = 0; kw < 3; ++kw) {
        int x = w + kw - 1;
        if ((unsigned)x >= HW_) continue;
        acc += xp[(size_t)ci * PLANE + y * HW_ + x] * wp[ci * 9 + kh * 3 + kw];
      }
    }
  }
  out[idx] = acc;
}

extern "C" void kernel_launch(void* const* d_in, const int* in_sizes, int n_in,
                              void* d_out, int out_size, void* d_ws, size_t ws_size,
                              hipStream_t stream) {
  (void)in_sizes; (void)n_in; (void)out_size;
  const float* X = (const float*)d_in[0];
  const float* W = (const float*)d_in[1];
  const float* b = (const float*)d_in[2];
  float* out = (float*)d_out;
  if (ws_size >= WS_NEED) {
    unsigned short* Xt = (unsigned short*)d_ws;
    unsigned short* Wp = (unsigned short*)((char*)d_ws + XT_BYTES);
    prep_x<<<1600, 256, 0, stream>>>(X, Xt);
    prep_w<<<144, 256, 0, stream>>>(W, Wp);
    conv_gemm<<<784, 256, 0, stream>>>(Xt, Wp, b, out);
  } else {
    conv_naive<<<(NB * CO_ * PLANE + 255) / 256, 256, 0, stream>>>(X, W, b, out);
  }
}

// Round 2
// 63.425 us; speedup vs baseline: 1.0768x; 1.0768x over previous
//
#include <hip/hip_runtime.h>

typedef __attribute__((ext_vector_type(8))) short short8;
typedef __attribute__((ext_vector_type(4))) float f32x4;

#define CI    128
#define CO_   256
#define HW_   56
#define PLANE 3136
#define NB    16
#define STOT  50176
#define KTOT  1152
#define OUTN  802816   // CO_*PLANE

// ws layout: [0, 12845056) Xt bf16 NHWC ; [12845056, +589824) Wpre bf16 (LDS-image order) ; then 256B zeros
#define XT_BYTES   12845056ull
#define WP_USHORTS 294912
#define WS_NEED    (12845056ull + 589824ull + 256ull)

__device__ __forceinline__ unsigned short f2bf(float f) {
  unsigned u = __float_as_uint(f);
  u += 0x7FFFu + ((u >> 16) & 1u);   // RNE
  return (unsigned short)(u >> 16);
}

__device__ __forceinline__ void gload16(void* lds, const void* g) {
  __builtin_amdgcn_global_load_lds(
      (const __attribute__((address_space(1))) unsigned int*)g,
      (__attribute__((address_space(3))) unsigned int*)lds, 16, 0, 0);
}

// ---------------- prep_x: NCHW fp32 -> NHWC bf16 (tiled transpose) ----------------
__global__ __launch_bounds__(256) void prep_x(const float* __restrict__ X,
                                              unsigned short* __restrict__ Xt) {
  __shared__ __align__(16) unsigned short tile[32][132];
  const int t = threadIdx.x;
  const int bx = blockIdx.x;
  const int n   = bx / 100;
  const int rem = bx % 100;
  const int cib = rem / 25;
  const int spb = rem % 25;
  const int sp0 = spb * 128;
  const float* src = X + (size_t)(n * CI + cib * 32) * PLANE;
#pragma unroll
  for (int j = 0; j < 4; ++j) {
    int f = t + 256 * j;            // 0..1023
    int ci  = f >> 5;               // 0..31
    int sp4 = (f & 31) * 4;         // 0..124
    if (sp0 + sp4 < PLANE) {
      f32x4 v = *(const f32x4*)(src + (size_t)ci * PLANE + sp0 + sp4);
#pragma unroll
      for (int e = 0; e < 4; ++e) tile[ci][sp4 + e] = f2bf(v[e]);
    }
  }
  __syncthreads();
  unsigned short* dst = Xt + ((size_t)n * PLANE + sp0) * CI + cib * 32;
#pragma unroll
  for (int j = 0; j < 2; ++j) {
    int g = t + 256 * j;            // 0..511
    int sp = g >> 2;                // 0..127
    int q  = g & 3;                 // 0..3 (8-ci chunk)
    if (sp0 + sp < PLANE) {
      short8 v;
#pragma unroll
      for (int e = 0; e < 8; ++e) v[e] = (short)tile[q * 8 + e][sp];
      *(short8*)(dst + (size_t)sp * CI + q * 8) = v;
    }
  }
}

// ---------------- prep_w: OIHW fp32 -> Wpre bf16 in LDS-image (pre-swizzled) order ----------------
// chunk p within an 8KB (r,cb,mt) block: col=p>>2, kg=(p&3)^((col>>1)&3), data = W[co][cb*32+kg*8+e][r]
__global__ __launch_bounds__(256) void prep_w(const float* __restrict__ W,
                                              unsigned short* __restrict__ Wp) {
  const int u = blockIdx.x * 256 + threadIdx.x;  // 0..36863
  const int rcbmt = u >> 9;          // 0..71 = ((r*4+cb)*2+mt)
  const int p     = u & 511;
  const int mt  = rcbmt & 1;
  const int rcb = rcbmt >> 1;        // 0..35
  const int cb  = rcb & 3;
  const int r   = rcb >> 2;          // 0..8
  const int col = p >> 2;            // co_local 0..127
  const int kg  = (p & 3) ^ ((col >> 1) & 3);   // granule-spreading swizzle
  const int co  = mt * 128 + col;
  const int ci0 = cb * 32 + kg * 8;
  short8 v;
#pragma unroll
  for (int e = 0; e < 8; ++e)
    v[e] = (short)f2bf(W[(size_t)co * KTOT + (size_t)(ci0 + e) * 9 + r]);
  *(short8*)(Wp + (size_t)u * 8) = v;
  if (u < 16) {                       // 256B zeros region right after Wpre
    short8 z = {0, 0, 0, 0, 0, 0, 0, 0};
    *(short8*)(Wp + WP_USHORTS + u * 8) = z;
  }
}

// ---------------- conv_gemm: implicit GEMM, bf16 MFMA, double-buffered 1-barrier/step ----------------
// grid 784 = 2 co-tiles * 392 sp-tiles ; block 256 = 4 waves (2x2), each wave 64x64 out
__global__ __launch_bounds__(256) void conv_gemm(const unsigned short* __restrict__ Xt,
                                                 const unsigned short* __restrict__ Wp,
                                                 const float* __restrict__ bias,
                                                 float* __restrict__ out) {
  __shared__ __align__(1024) char smem[32768];  // 2 buffers x (A 8KB | B 8KB)
  const int t    = threadIdx.x;
  const int lane = t & 63;
  const int wid  = t >> 6;
  const int wm   = wid >> 1, wn = wid & 1;

  int bx = blockIdx.x;
  bx = (bx & 7) * 98 + (bx >> 3);     // XCD swizzle, bijective (784 = 8*98)
  const int mt  = bx & 1;
  const int spt = bx >> 1;

  // --- staging roles (B side): thread t covers LDS chunks p=t (S0) and p=256+t (S1)
  const int kgB = (t & 3) ^ ((t >> 3) & 3);   // swizzle: kg = q ^ ((sp_local>>1)&3)
  const int S0 = spt * 128 + (t >> 2);
  const int S1 = S0 + 64;
  const int hw0 = S0 % PLANE, h0 = hw0 / HW_, w0 = hw0 - h0 * HW_;
  const int hw1 = S1 % PLANE, h1 = hw1 / HW_, w1 = hw1 - h1 * HW_;

  const char* xb0  = (const char*)Xt + ((size_t)S0 * CI + kgB * 8) * 2;
  const char* xb1  = (const char*)Xt + ((size_t)S1 * CI + kgB * 8) * 2;
  const char* zb   = (const char*)(Wp + WP_USHORTS) + kgB * 16;
  const char* wpA  = (const char*)Wp + mt * 8192 + t * 16;

  // fragment read offsets (within a buffer); swizzle q = (k-half) ^ ((row>>1)&3)
  const int swz  = ((lane >> 4) ^ ((lane >> 1) & 3)) * 16;
  const int aoff = (wm * 64 + (lane & 15)) * 64 + swz;
  const int boff = 8192 + (wn * 64 + (lane & 15)) * 64 + swz;
  char* wvbase = smem + wid * 1024;   // wave-uniform LDS staging base (+ lane*16 by HW)

  f32x4 acc[4][4];
  const f32x4 zf = {0.f, 0.f, 0.f, 0.f};
#pragma unroll
  for (int m = 0; m < 4; ++m)
#pragma unroll
    for (int n = 0; n < 4; ++n) acc[m][n] = zf;

  auto STAGE = [&](int s) {
    const int r_  = s >> 2, cb_ = s & 3;
    const int dh_ = r_ / 3 - 1, dw_ = r_ % 3 - 1;
    const int ro_ = dh_ * HW_ + dw_;          // spatial shift in elements
    char* dst = wvbase + (s & 1) * 16384;
    const char* as = wpA + r_ * 65536 + cb_ * 16384;
    gload16(dst, as);                          // A rows 0..63   (per wave 1KB slice)
    gload16(dst + 4096, as + 4096);            // A rows 64..127
    const bool v0 = ((unsigned)(h0 + dh_) < HW_) & ((unsigned)(w0 + dw_) < HW_);
    const bool v1 = ((unsigned)(h1 + dh_) < HW_) & ((unsigned)(w1 + dw_) < HW_);
    const char* b0 = v0 ? xb0 + ro_ * 256 + cb_ * 64 : zb + cb_ * 64;
    const char* b1 = v1 ? xb1 + ro_ * 256 + cb_ * 64 : zb + cb_ * 64;
    gload16(dst + 8192, b0);                   // B sp 0..63
    gload16(dst + 12288, b1);                  // B sp 64..127
  };

  STAGE(0);
  __syncthreads();                             // drain prologue loads

#pragma unroll
  for (int s = 0; s < 36; ++s) {
    if (s < 35) STAGE(s + 1);                  // issue next-step loads first (T3 2-phase)
    const char* rb = smem + (s & 1) * 16384;
    short8 a[4], b[4];
#pragma unroll
    for (int m = 0; m < 4; ++m) a[m] = *(const short8*)(rb + aoff + m * 1024);
#pragma unroll
    for (int n = 0; n < 4; ++n) b[n] = *(const short8*)(rb + boff + n * 1024);
#pragma unroll
    for (int m = 0; m < 4; ++m)
#pragma unroll
      for (int n = 0; n < 4; ++n)
        acc[m][n] = __builtin_amdgcn_mfma_f32_16x16x32_bf16(a[m], b[n], acc[m][n], 0, 0, 0);
    __syncthreads();                           // one vmcnt(0)+barrier per step
  }

  // ---- epilogue: D row = co = (lane>>4)*4+reg, col = sp = lane&15
  float bv[4][4];
#pragma unroll
  for (int mf = 0; mf < 4; ++mf) {
    int cobase = mt * 128 + wm * 64 + mf * 16 + (lane >> 4) * 4;
#pragma unroll
    for (int r2 = 0; r2 < 4; ++r2) bv[mf][r2] = bias[cobase + r2];
  }
#pragma unroll
  for (int nf = 0; nf < 4; ++nf) {
    int S = spt * 128 + wn * 64 + nf * 16 + (lane & 15);
    int n = S / PLANE, hw = S - n * PLANE;
    float* ob = out + (size_t)n * OUTN + hw;
#pragma unroll
    for (int mf = 0; mf < 4; ++mf) {
      int cobase = mt * 128 + wm * 64 + mf * 16 + (lane >> 4) * 4;
#pragma unroll
      for (int r2 = 0; r2 < 4; ++r2)
        ob[(size_t)(cobase + r2) * PLANE] = acc[mf][nf][r2] + bv[mf][r2];
    }
  }
}

// ---------------- fallback: naive direct conv (only if ws too small) ----------------
__global__ __launch_bounds__(256) void conv_naive(const float* __restrict__ X,
                                                  const float* __restrict__ W,
                                                  const float* __restrict__ bias,
                                                  float* __restrict__ out) {
  int idx = blockIdx.x * 256 + threadIdx.x;
  int hw = idx % PLANE;
  int co = (idx / PLANE) & 255;
  int n  = idx / (PLANE * 256);
  int h = hw / HW_, w = hw - h * HW_;
  float acc = bias[co];
  const float* xp = X + (size_t)n * CI * PLANE;
  const float* wp = W + (size_t)co * KTOT;
  for (int ci = 0; ci < CI; ++ci) {
#pragma unroll
    for (int kh = 0; kh < 3; ++kh) {
      int y = h + kh - 1;
      if ((unsigned)y >= HW_) continue;
#pragma unroll
      for (int kw = 0; kw < 3; ++kw) {
        int x = w + kw - 1;
        if ((unsigned)x >= HW_) continue;
        acc += xp[(size_t)ci * PLANE + y * HW_ + x] * wp[ci * 9 + kh * 3 + kw];
      }
    }
  }
  out[idx] = acc;
}

extern "C" void kernel_launch(void* const* d_in, const int* in_sizes, int n_in,
                              void* d_out, int out_size, void* d_ws, size_t ws_size,
                              hipStream_t stream) {
  (void)in_sizes; (void)n_in; (void)out_size;
  const float* X = (const float*)d_in[0];
  const float* W = (const float*)d_in[1];
  const float* b = (const float*)d_in[2];
  float* out = (float*)d_out;
  if (ws_size >= WS_NEED) {
    unsigned short* Xt = (unsigned short*)d_ws;
    unsigned short* Wp = (unsigned short*)((char*)d_ws + XT_BYTES);
    prep_x<<<1600, 256, 0, stream>>>(X, Xt);
    prep_w<<<144, 256, 0, stream>>>(W, Wp);
    conv_gemm<<<784, 256, 0, stream>>>(Xt, Wp, b, out);
  } else {
    conv_naive<<<(NB * CO_ * PLANE + 255) / 256, 256, 0, stream>>>(X, W, b, out);
  }
}

// Round 3
// 55.089 us; speedup vs baseline: 1.2398x; 1.1513x over previous
//
#include <hip/hip_runtime.h>

typedef __attribute__((ext_vector_type(8))) short short8;
typedef __attribute__((ext_vector_type(4))) float f32x4;

#define CI    128
#define CO_   256
#define HW_   56
#define PLANE 3136
#define NB    16
#define STOT  50176
#define KTOT  1152
#define OUTN  802816   // CO_*PLANE

// ws layout: [0, 12845056) Xt bf16 NHWC ; [12845056, +589824) Wpre bf16 (LDS-image order) ; then 256B zeros
#define XT_BYTES   12845056ull
#define WP_USHORTS 294912
#define WS_NEED    (12845056ull + 589824ull + 256ull)

__device__ __forceinline__ unsigned short f2bf(float f) {
  unsigned u = __float_as_uint(f);
  u += 0x7FFFu + ((u >> 16) & 1u);   // RNE
  return (unsigned short)(u >> 16);
}

__device__ __forceinline__ void gload16(void* lds, const void* g) {
  __builtin_amdgcn_global_load_lds(
      (const __attribute__((address_space(1))) unsigned int*)g,
      (__attribute__((address_space(3))) unsigned int*)lds, 16, 0, 0);
}

template <int N> __device__ __forceinline__ void vmwait() {
  asm volatile("s_waitcnt vmcnt(%0)" ::"n"(N) : "memory");
}

// ---------------- prep_x: NCHW fp32 -> NHWC bf16 (tiled transpose) ----------------
__global__ __launch_bounds__(256) void prep_x(const float* __restrict__ X,
                                              unsigned short* __restrict__ Xt) {
  __shared__ __align__(16) unsigned short tile[32][132];
  const int t = threadIdx.x;
  const int bx = blockIdx.x;
  const int n   = bx / 100;
  const int rem = bx % 100;
  const int cib = rem / 25;
  const int spb = rem % 25;
  const int sp0 = spb * 128;
  const float* src = X + (size_t)(n * CI + cib * 32) * PLANE;
#pragma unroll
  for (int j = 0; j < 4; ++j) {
    int f = t + 256 * j;            // 0..1023
    int ci  = f >> 5;               // 0..31
    int sp4 = (f & 31) * 4;         // 0..124
    if (sp0 + sp4 < PLANE) {
      f32x4 v = *(const f32x4*)(src + (size_t)ci * PLANE + sp0 + sp4);
#pragma unroll
      for (int e = 0; e < 4; ++e) tile[ci][sp4 + e] = f2bf(v[e]);
    }
  }
  __syncthreads();
  unsigned short* dst = Xt + ((size_t)n * PLANE + sp0) * CI + cib * 32;
#pragma unroll
  for (int j = 0; j < 2; ++j) {
    int g = t + 256 * j;            // 0..511
    int sp = g >> 2;                // 0..127
    int q  = g & 3;                 // 0..3 (8-ci chunk)
    if (sp0 + sp < PLANE) {
      short8 v;
#pragma unroll
      for (int e = 0; e < 8; ++e) v[e] = (short)tile[q * 8 + e][sp];
      *(short8*)(dst + (size_t)sp * CI + q * 8) = v;
    }
  }
}

// ---------------- prep_w: OIHW fp32 -> Wpre bf16 in LDS-image (pre-swizzled) order ----------------
// chunk p within an 8KB (r,cb,mt) block: col=p>>2, kg=(p&3)^((col>>1)&3), data = W[co][cb*32+kg*8+e][r]
__global__ __launch_bounds__(256) void prep_w(const float* __restrict__ W,
                                              unsigned short* __restrict__ Wp) {
  const int u = blockIdx.x * 256 + threadIdx.x;  // 0..36863
  const int rcbmt = u >> 9;          // 0..71 = ((r*4+cb)*2+mt)
  const int p     = u & 511;
  const int mt  = rcbmt & 1;
  const int rcb = rcbmt >> 1;        // 0..35
  const int cb  = rcb & 3;
  const int r   = rcb >> 2;          // 0..8
  const int col = p >> 2;            // co_local 0..127
  const int kg  = (p & 3) ^ ((col >> 1) & 3);   // granule-spreading swizzle
  const int co  = mt * 128 + col;
  const int ci0 = cb * 32 + kg * 8;
  short8 v;
#pragma unroll
  for (int e = 0; e < 8; ++e)
    v[e] = (short)f2bf(W[(size_t)co * KTOT + (size_t)(ci0 + e) * 9 + r]);
  *(short8*)(Wp + (size_t)u * 8) = v;
  if (u < 16) {                       // 256B zeros region right after Wpre
    short8 z = {0, 0, 0, 0, 0, 0, 0, 0};
    *(short8*)(Wp + WP_USHORTS + u * 8) = z;
  }
}

// ---------------- conv_gemm: implicit GEMM, bf16 MFMA ----------------
// 3-deep LDS pipeline, counted vmcnt (T3+T4): loads issued at step s land by step s+3.
// grid 784 = 2 co-tiles * 392 sp-tiles ; block 256 = 4 waves (2x2), each wave 64x64 out
__global__ __launch_bounds__(256) void conv_gemm(const unsigned short* __restrict__ Xt,
                                                 const unsigned short* __restrict__ Wp,
                                                 const float* __restrict__ bias,
                                                 float* __restrict__ out) {
  __shared__ __align__(1024) char smem[49152];  // 3 buffers x (A 8KB | B 8KB)
  const int t    = threadIdx.x;
  const int lane = t & 63;
  const int wid  = t >> 6;
  const int wm   = wid >> 1, wn = wid & 1;

  int bx = blockIdx.x;
  bx = (bx & 7) * 98 + (bx >> 3);     // XCD swizzle, bijective (784 = 8*98)
  const int mt  = bx & 1;
  const int spt = bx >> 1;

  // --- staging roles (B side): thread t covers LDS chunks p=t (S0) and p=256+t (S1)
  const int kgB = (t & 3) ^ ((t >> 3) & 3);   // swizzle: kg = q ^ ((sp_local>>1)&3)
  const int S0 = spt * 128 + (t >> 2);
  const int S1 = S0 + 64;
  const int hw0 = S0 % PLANE, h0 = hw0 / HW_, w0 = hw0 - h0 * HW_;
  const int hw1 = S1 % PLANE, h1 = hw1 / HW_, w1 = hw1 - h1 * HW_;

  const char* xb0  = (const char*)Xt + ((size_t)S0 * CI + kgB * 8) * 2;
  const char* xb1  = (const char*)Xt + ((size_t)S1 * CI + kgB * 8) * 2;
  const char* zb   = (const char*)(Wp + WP_USHORTS) + kgB * 16;
  const char* wpA  = (const char*)Wp + mt * 8192 + t * 16;

  // fragment read offsets (within a buffer); swizzle q = (k-half) ^ ((row>>1)&3)
  const int swz  = ((lane >> 4) ^ ((lane >> 1) & 3)) * 16;
  const int aoff = (wm * 64 + (lane & 15)) * 64 + swz;
  const int boff = 8192 + (wn * 64 + (lane & 15)) * 64 + swz;

  f32x4 acc[4][4];
  const f32x4 zf = {0.f, 0.f, 0.f, 0.f};
#pragma unroll
  for (int m = 0; m < 4; ++m)
#pragma unroll
    for (int n = 0; n < 4; ++n) acc[m][n] = zf;

  auto STAGE = [&](int s) {
    const int r_  = (s >> 2) , cb_ = s & 3;
    const int dh_ = r_ / 3 - 1, dw_ = r_ % 3 - 1;
    const int ro_ = dh_ * HW_ + dw_;          // spatial shift in elements
    char* dst = smem + (s % 3) * 16384 + wid * 1024;
    const char* as = wpA + r_ * 65536 + cb_ * 16384;
    gload16(dst, as);                          // A rows 0..63   (per wave 1KB slice)
    gload16(dst + 4096, as + 4096);            // A rows 64..127
    const bool v0 = ((unsigned)(h0 + dh_) < HW_) & ((unsigned)(w0 + dw_) < HW_);
    const bool v1 = ((unsigned)(h1 + dh_) < HW_) & ((unsigned)(w1 + dw_) < HW_);
    const char* b0 = v0 ? xb0 + ro_ * 256 + cb_ * 64 : zb + cb_ * 64;
    const char* b1 = v1 ? xb1 + ro_ * 256 + cb_ * 64 : zb + cb_ * 64;
    gload16(dst + 8192, b0);                   // B sp 0..63
    gload16(dst + 12288, b1);                  // B sp 64..127
  };

  STAGE(0);
  STAGE(1);
  STAGE(2);

#pragma unroll
  for (int s = 0; s < 36; ++s) {
    // counted wait: stage s's 4 loads landed; stages s+1,s+2 (8 loads) stay in flight
    if (s <= 33)      vmwait<8>();
    else if (s == 34) vmwait<4>();
    else              vmwait<0>();
    __builtin_amdgcn_s_barrier();              // all threads' stage-s data visible

    const char* rb = smem + (s % 3) * 16384;
    short8 a[4], b[4];
#pragma unroll
    for (int m = 0; m < 4; ++m) a[m] = *(const short8*)(rb + aoff + m * 1024);
#pragma unroll
    for (int n = 0; n < 4; ++n) b[n] = *(const short8*)(rb + boff + n * 1024);
#pragma unroll
    for (int m = 0; m < 4; ++m)
#pragma unroll
      for (int n = 0; n < 4; ++n)
        acc[m][n] = __builtin_amdgcn_mfma_f32_16x16x32_bf16(a[m], b[n], acc[m][n], 0, 0, 0);

    if (s < 33) {
      __builtin_amdgcn_s_barrier();            // all waves done reading buf[s%3] (WAR)
      STAGE(s + 3);                            // overwrite it with stage s+3
    }
  }

  // ---- epilogue: D row = co = (lane>>4)*4+reg, col = sp = lane&15
  float bv[4][4];
#pragma unroll
  for (int mf = 0; mf < 4; ++mf) {
    int cobase = mt * 128 + wm * 64 + mf * 16 + (lane >> 4) * 4;
#pragma unroll
    for (int r2 = 0; r2 < 4; ++r2) bv[mf][r2] = bias[cobase + r2];
  }
#pragma unroll
  for (int nf = 0; nf < 4; ++nf) {
    int S = spt * 128 + wn * 64 + nf * 16 + (lane & 15);
    int n = S / PLANE, hw = S - n * PLANE;
    float* ob = out + (size_t)n * OUTN + hw;
#pragma unroll
    for (int mf = 0; mf < 4; ++mf) {
      int cobase = mt * 128 + wm * 64 + mf * 16 + (lane >> 4) * 4;
#pragma unroll
      for (int r2 = 0; r2 < 4; ++r2)
        ob[(size_t)(cobase + r2) * PLANE] = acc[mf][nf][r2] + bv[mf][r2];
    }
  }
}

// ---------------- fallback: naive direct conv (only if ws too small) ----------------
__global__ __launch_bounds__(256) void conv_naive(const float* __restrict__ X,
                                                  const float* __restrict__ W,
                                                  const float* __restrict__ bias,
                                                  float* __restrict__ out) {
  int idx = blockIdx.x * 256 + threadIdx.x;
  int hw = idx % PLANE;
  int co = (idx / PLANE) & 255;
  int n  = idx / (PLANE * 256);
  int h = hw / HW_, w = hw - h * HW_;
  float acc = bias[co];
  const float* xp = X + (size_t)n * CI * PLANE;
  const float* wp = W + (size_t)co * KTOT;
  for (int ci = 0; ci < CI; ++ci) {
#pragma unroll
    for (int kh = 0; kh < 3; ++kh) {
      int y = h + kh - 1;
      if ((unsigned)y >= HW_) continue;
#pragma unroll
      for (int kw = 0; kw < 3; ++kw) {
        int x = w + kw - 1;
        if ((unsigned)x >= HW_) continue;
        acc += xp[(size_t)ci * PLANE + y * HW_ + x] * wp[ci * 9 + kh * 3 + kw];
      }
    }
  }
  out[idx] = acc;
}

extern "C" void kernel_launch(void* const* d_in, const int* in_sizes, int n_in,
                              void* d_out, int out_size, void* d_ws, size_t ws_size,
                              hipStream_t stream) {
  (void)in_sizes; (void)n_in; (void)out_size;
  const float* X = (const float*)d_in[0];
  const float* W = (const float*)d_in[1];
  const float* b = (const float*)d_in[2];
  float* out = (float*)d_out;
  if (ws_size >= WS_NEED) {
    unsigned short* Xt = (unsigned short*)d_ws;
    unsigned short* Wp = (unsigned short*)((char*)d_ws + XT_BYTES);
    prep_x<<<1600, 256, 0, stream>>>(X, Xt);
    prep_w<<<144, 256, 0, stream>>>(W, Wp);
    conv_gemm<<<784, 256, 0, stream>>>(Xt, Wp, b, out);
  } else {
    conv_naive<<<(NB * CO_ * PLANE + 255) / 256, 256, 0, stream>>>(X, W, b, out);
  }
}

// Round 4
// 50.956 us; speedup vs baseline: 1.3403x; 1.0811x over previous
//
#include <hip/hip_runtime.h>

typedef __attribute__((ext_vector_type(8))) short short8;
typedef __attribute__((ext_vector_type(4))) float f32x4;

#define CI    128
#define CO_   256
#define HW_   56
#define PLANE 3136
#define NB    16
#define STOT  50176
#define KTOT  1152
#define OUTN  802816   // CO_*PLANE

// ws layout: [0, 12845056) Xt bf16 NHWC ; [12845056, +589824) Wpre bf16 ; then 256B zeros
#define XT_BYTES   12845056ull
#define WP_USHORTS 294912
#define WS_NEED    (12845056ull + 589824ull + 256ull)

__device__ __forceinline__ unsigned short f2bf(float f) {
  unsigned u = __float_as_uint(f);
  u += 0x7FFFu + ((u >> 16) & 1u);   // RNE
  return (unsigned short)(u >> 16);
}

__device__ __forceinline__ void gload16(void* lds, const void* g) {
  __builtin_amdgcn_global_load_lds(
      (const __attribute__((address_space(1))) unsigned int*)g,
      (__attribute__((address_space(3))) unsigned int*)lds, 16, 0, 0);
}

// ---------------- fused prep: blocks 0..1599 = prep_x ; 1600..1743 = prep_w ----------------
__global__ __launch_bounds__(256) void prep_fused(const float* __restrict__ X,
                                                  const float* __restrict__ W,
                                                  unsigned short* __restrict__ Xt,
                                                  unsigned short* __restrict__ Wp) {
  const int t = threadIdx.x;
  if (blockIdx.x < 1600) {
    // ---- prep_x: NCHW fp32 -> NHWC bf16 (tiled transpose)
    __shared__ __align__(16) unsigned short tile[32][132];
    const int bx = blockIdx.x;
    const int n   = bx / 100;
    const int rem = bx % 100;
    const int cib = rem / 25;
    const int spb = rem % 25;
    const int sp0 = spb * 128;
    const float* src = X + (size_t)(n * CI + cib * 32) * PLANE;
#pragma unroll
    for (int j = 0; j < 4; ++j) {
      int f = t + 256 * j;
      int ci  = f >> 5;
      int sp4 = (f & 31) * 4;
      if (sp0 + sp4 < PLANE) {
        f32x4 v = *(const f32x4*)(src + (size_t)ci * PLANE + sp0 + sp4);
#pragma unroll
        for (int e = 0; e < 4; ++e) tile[ci][sp4 + e] = f2bf(v[e]);
      }
    }
    __syncthreads();
    unsigned short* dst = Xt + ((size_t)n * PLANE + sp0) * CI + cib * 32;
#pragma unroll
    for (int j = 0; j < 2; ++j) {
      int g = t + 256 * j;
      int sp = g >> 2;
      int q  = g & 3;
      if (sp0 + sp < PLANE) {
        short8 v;
#pragma unroll
        for (int e = 0; e < 8; ++e) v[e] = (short)tile[q * 8 + e][sp];
        *(short8*)(dst + (size_t)sp * CI + q * 8) = v;
      }
    }
  } else {
    // ---- prep_w: OIHW fp32 -> Wpre in the exact staged-LDS linear order.
    // chunk c = ((kt*4 + i)*512 + tt), i=(ks,half): holds
    //   W[co = half*128 + tt>>2][ci = (kt&1)*64 + ks*32 + ((tt&3)^((tt>>3)&3))*8 + e][r = kt>>1]
    const int c = (blockIdx.x - 1600) * 256 + t;   // 0..36863
    const int kt   = c >> 11;
    const int i3   = (c >> 9) & 3;
    const int tt   = c & 511;
    const int ks   = i3 >> 1;
    const int half = i3 & 1;
    const int row  = half * 128 + (tt >> 2);
    const int swzq = (tt & 3) ^ ((tt >> 3) & 3);
    const int r    = kt >> 1;
    const int cib  = kt & 1;
    const int ci0  = cib * 64 + ks * 32 + swzq * 8;
    short8 v;
#pragma unroll
    for (int e = 0; e < 8; ++e)
      v[e] = (short)f2bf(W[(size_t)row * KTOT + (size_t)(ci0 + e) * 9 + r]);
    *(short8*)(Wp + (size_t)c * 8) = v;
    if (c < 16) {
      short8 z = {0, 0, 0, 0, 0, 0, 0, 0};
      *(short8*)(Wp + WP_USHORTS + c * 8) = z;
    }
  }
}

// quadrant MFMA: 16 mfma over acc[MH*4+m][NH*2+n], wrapped in setprio (T5)
#define MFMA_Q(MH, NH)                                                                 \
  __builtin_amdgcn_s_setprio(1);                                                       \
  _Pragma("unroll") for (int ks = 0; ks < 2; ++ks)                                     \
  _Pragma("unroll") for (int m = 0; m < 4; ++m)                                        \
  _Pragma("unroll") for (int n = 0; n < 2; ++n)                                        \
    acc[(MH)*4 + m][(NH)*2 + n] = __builtin_amdgcn_mfma_f32_16x16x32_bf16(             \
        aF[m][ks], bF[(NH)*2 + n][ks], acc[(MH)*4 + m][(NH)*2 + n], 0, 0, 0);          \
  __builtin_amdgcn_s_setprio(0);

// ---------------- conv_gemm: 256x256 tile, 8 waves, 4-phase K64 pipeline (m201-style) --------
// grid 196 = sp-tiles of 256 ; block 512 = 8 waves (2M x 4N), wave tile 128co x 64sp
__global__ __launch_bounds__(512, 2) void conv_gemm(const unsigned short* __restrict__ Xt,
                                                    const unsigned short* __restrict__ Wp,
                                                    const float* __restrict__ bias,
                                                    float* __restrict__ out) {
  __shared__ __align__(1024) char smem[131072];  // 2 buf x (A 32K | B 32K); [ks][half][row64B]
  const int t    = threadIdx.x;
  const int lane = t & 63;
  const int wid  = t >> 6;
  const int wm   = wid >> 2, wn = wid & 3;

  // bijective XCD swizzle for 196 blocks (q=24, r=4)
  const int orig = blockIdx.x;
  const int xcd = orig & 7, idx = orig >> 3;
  const int spt = (xcd < 4 ? xcd * 25 : 100 + (xcd - 4) * 24) + idx;   // 0..195

  // --- staging precompute (each thread: one sp-row per half)
  const int kgB = (t & 3) ^ ((t >> 3) & 3);
  const int S0 = spt * 256 + (t >> 2);
  const int S1 = S0 + 128;
  const int hw0 = S0 % PLANE, h0 = hw0 / HW_, w0 = hw0 - h0 * HW_;
  const int hw1 = S1 % PLANE, h1 = hw1 / HW_, w1 = hw1 - h1 * HW_;
  int vm0 = 0, vm1 = 0;
#pragma unroll
  for (int r = 0; r < 9; ++r) {
    int dh = r / 3 - 1, dw = r % 3 - 1;
    vm0 |= (int)(((unsigned)(h0 + dh) < HW_) & ((unsigned)(w0 + dw) < HW_)) << r;
    vm1 |= (int)(((unsigned)(h1 + dh) < HW_) & ((unsigned)(w1 + dw) < HW_)) << r;
  }
  const char* xb0 = (const char*)Xt + ((size_t)S0 * CI + kgB * 8) * 2;
  const char* xb1 = (const char*)Xt + ((size_t)S1 * CI + kgB * 8) * 2;
  const char* zb  = (const char*)(Wp + WP_USHORTS) + (t & 3) * 16;
  const char* wpA = (const char*)Wp + t * 16;

  // fragment read offsets (64B rows, granule swizzle q^((row>>1)&3) -> lane-constant)
  const int swz  = ((lane >> 4) ^ ((lane >> 1) & 3)) * 16;
  const int aoff = (wm * 128 + (lane & 15)) * 64 + swz;            // + ks*16384 + m*1024
  const int boff = 32768 + (wn * 64 + (lane & 15)) * 64 + swz;     // + ks*16384 + n*1024

  f32x4 acc[8][4];
  const f32x4 zf = {0.f, 0.f, 0.f, 0.f};
#pragma unroll
  for (int m = 0; m < 8; ++m)
#pragma unroll
    for (int n = 0; n < 4; ++n) acc[m][n] = zf;

  auto SA = [&](int kt1, int i, char* buf) {
    gload16(buf + (i >> 1) * 16384 + (i & 1) * 8192 + wid * 1024,
            wpA + (size_t)(kt1 * 4 + i) * 8192);
  };
  auto SB = [&](int kt1, int i, char* buf) {
    const int ks = i >> 1, half = i & 1;
    const int r = kt1 >> 1, cib = kt1 & 1;
    const int dh = r / 3 - 1, dw = r % 3 - 1;
    const int ro = dh * HW_ + dw;
    const bool v = ((half ? vm1 : vm0) >> r) & 1;
    const char* src = (half ? xb1 : xb0) + ro * 256 + cib * 128 + ks * 64;
    gload16(buf + 32768 + ks * 16384 + half * 8192 + wid * 1024, v ? src : zb);
  };

  // prologue: stage tile 0 fully
  {
    char* b0 = smem;
#pragma unroll
    for (int i = 0; i < 4; ++i) { SA(0, i, b0); SB(0, i, b0); }
  }
  __syncthreads();

#pragma unroll
  for (int kt = 0; kt < 18; ++kt) {
    char* cur = smem + (kt & 1) * 65536;
    char* nxt = smem + ((kt + 1) & 1) * 65536;
    const char* ca = cur + aoff;
    const char* cb = cur + boff;
    short8 aF[4][2], bF[4][2];

    // ---- phase 0: read a(mh0) + b(n0,n1); stage A0,A1,B0; mfma Q(0,0)
#pragma unroll
    for (int m = 0; m < 4; ++m) {
      aF[m][0] = *(const short8*)(ca + m * 1024);
      aF[m][1] = *(const short8*)(ca + 16384 + m * 1024);
    }
#pragma unroll
    for (int n = 0; n < 2; ++n) {
      bF[n][0] = *(const short8*)(cb + n * 1024);
      bF[n][1] = *(const short8*)(cb + 16384 + n * 1024);
    }
    if (kt < 17) { SA(kt + 1, 0, nxt); SA(kt + 1, 1, nxt); SB(kt + 1, 0, nxt); }
    __builtin_amdgcn_s_barrier();
    MFMA_Q(0, 0)
    __builtin_amdgcn_s_barrier();

    // ---- phase 1: read b(n2,n3); stage A2,A3,B1; mfma Q(0,1)
#pragma unroll
    for (int n = 0; n < 2; ++n) {
      bF[2 + n][0] = *(const short8*)(cb + (2 + n) * 1024);
      bF[2 + n][1] = *(const short8*)(cb + 16384 + (2 + n) * 1024);
    }
    if (kt < 17) { SA(kt + 1, 2, nxt); SA(kt + 1, 3, nxt); SB(kt + 1, 1, nxt); }
    __builtin_amdgcn_s_barrier();
    MFMA_Q(0, 1)
    __builtin_amdgcn_s_barrier();

    // ---- phase 2: read a(mh1); stage B2,B3; mfma Q(1,1)
#pragma unroll
    for (int m = 0; m < 4; ++m) {
      aF[m][0] = *(const short8*)(ca + 4096 + m * 1024);
      aF[m][1] = *(const short8*)(ca + 16384 + 4096 + m * 1024);
    }
    if (kt < 17) { SB(kt + 1, 2, nxt); SB(kt + 1, 3, nxt); }
    __builtin_amdgcn_s_barrier();
    MFMA_Q(1, 1)
    __builtin_amdgcn_s_barrier();

    // ---- phase 3: mfma Q(1,0) (frags already live)
    MFMA_Q(1, 0)

    __syncthreads();   // drains next tile's 8 stage-loads (>=1200cy old) + LDS fence
  }

  // ---- epilogue: D row = co = (lane>>4)*4+reg, col = sp = lane&15
#pragma unroll
  for (int nf = 0; nf < 4; ++nf) {
    int S = spt * 256 + wn * 64 + nf * 16 + (lane & 15);
    int nimg = S / PLANE, hw = S - nimg * PLANE;
    float* ob = out + (size_t)nimg * OUTN + hw;
#pragma unroll
    for (int mf = 0; mf < 8; ++mf) {
      int cob = wm * 128 + mf * 16 + (lane >> 4) * 4;
#pragma unroll
      for (int r2 = 0; r2 < 4; ++r2)
        ob[(size_t)(cob + r2) * PLANE] = acc[mf][nf][r2] + bias[cob + r2];
    }
  }
}

// ---------------- fallback: naive direct conv (only if ws too small) ----------------
__global__ __launch_bounds__(256) void conv_naive(const float* __restrict__ X,
                                                  const float* __restrict__ W,
                                                  const float* __restrict__ bias,
                                                  float* __restrict__ out) {
  int idx = blockIdx.x * 256 + threadIdx.x;
  int hw = idx % PLANE;
  int co = (idx / PLANE) & 255;
  int n  = idx / (PLANE * 256);
  int h = hw / HW_, w = hw - h * HW_;
  float acc = bias[co];
  const float* xp = X + (size_t)n * CI * PLANE;
  const float* wp = W + (size_t)co * KTOT;
  for (int ci = 0; ci < CI; ++ci) {
#pragma unroll
    for (int kh = 0; kh < 3; ++kh) {
      int y = h + kh - 1;
      if ((unsigned)y >= HW_) continue;
#pragma unroll
      for (int kw = 0; kw < 3; ++kw) {
        int x = w + kw - 1;
        if ((unsigned)x >= HW_) continue;
        acc += xp[(size_t)ci * PLANE + y * HW_ + x] * wp[ci * 9 + kh * 3 + kw];
      }
    }
  }
  out[idx] = acc;
}

extern "C" void kernel_launch(void* const* d_in, const int* in_sizes, int n_in,
                              void* d_out, int out_size, void* d_ws, size_t ws_size,
                              hipStream_t stream) {
  (void)in_sizes; (void)n_in; (void)out_size;
  const float* X = (const float*)d_in[0];
  const float* W = (const float*)d_in[1];
  const float* b = (const float*)d_in[2];
  float* out = (float*)d_out;
  if (ws_size >= WS_NEED) {
    unsigned short* Xt = (unsigned short*)d_ws;
    unsigned short* Wp = (unsigned short*)((char*)d_ws + XT_BYTES);
    prep_fused<<<1744, 256, 0, stream>>>(X, W, Xt, Wp);
    conv_gemm<<<196, 512, 0, stream>>>(Xt, Wp, b, out);
  } else {
    conv_naive<<<(NB * CO_ * PLANE + 255) / 256, 256, 0, stream>>>(X, W, b, out);
  }
}

// Round 5
// 50.534 us; speedup vs baseline: 1.3515x; 1.0084x over previous
//
#include <hip/hip_runtime.h>

typedef __attribute__((ext_vector_type(8))) short short8;
typedef __attribute__((ext_vector_type(4))) float f32x4;

#define CI    128
#define CO_   256
#define HW_   56
#define PLANE 3136
#define NB    16
#define STOT  50176
#define KTOT  1152
#define OUTN  802816   // CO_*PLANE

// ws layout: [0, 12845056) Xt bf16 NHWC ; [12845056, +589824) Wpre bf16 ; then 256B zeros
#define XT_BYTES   12845056ull
#define WP_USHORTS 294912
#define WS_NEED    (12845056ull + 589824ull + 256ull)

__device__ __forceinline__ unsigned short f2bf(float f) {
  unsigned u = __float_as_uint(f);
  u += 0x7FFFu + ((u >> 16) & 1u);   // RNE
  return (unsigned short)(u >> 16);
}

__device__ __forceinline__ void gload16(void* lds, const void* g) {
  __builtin_amdgcn_global_load_lds(
      (const __attribute__((address_space(1))) unsigned int*)g,
      (__attribute__((address_space(3))) unsigned int*)lds, 16, 0, 0);
}

template <int N> __device__ __forceinline__ void vmwait() {
  asm volatile("s_waitcnt vmcnt(%0)" ::"n"(N) : "memory");
}

// ---------------- fused prep: blocks 0..1599 = prep_x ; 1600..1743 = prep_w ----------------
__global__ __launch_bounds__(256) void prep_fused(const float* __restrict__ X,
                                                  const float* __restrict__ W,
                                                  unsigned short* __restrict__ Xt,
                                                  unsigned short* __restrict__ Wp) {
  const int t = threadIdx.x;
  if (blockIdx.x < 1600) {
    // ---- prep_x: NCHW fp32 -> NHWC bf16 (tiled transpose)
    __shared__ __align__(16) unsigned short tile[32][132];
    const int bx = blockIdx.x;
    const int n   = bx / 100;
    const int rem = bx % 100;
    const int cib = rem / 25;
    const int spb = rem % 25;
    const int sp0 = spb * 128;
    const float* src = X + (size_t)(n * CI + cib * 32) * PLANE;
#pragma unroll
    for (int j = 0; j < 4; ++j) {
      int f = t + 256 * j;
      int ci  = f >> 5;
      int sp4 = (f & 31) * 4;
      if (sp0 + sp4 < PLANE) {
        f32x4 v = *(const f32x4*)(src + (size_t)ci * PLANE + sp0 + sp4);
#pragma unroll
        for (int e = 0; e < 4; ++e) tile[ci][sp4 + e] = f2bf(v[e]);
      }
    }
    __syncthreads();
    unsigned short* dst = Xt + ((size_t)n * PLANE + sp0) * CI + cib * 32;
#pragma unroll
    for (int j = 0; j < 2; ++j) {
      int g = t + 256 * j;
      int sp = g >> 2;
      int q  = g & 3;
      if (sp0 + sp < PLANE) {
        short8 v;
#pragma unroll
        for (int e = 0; e < 8; ++e) v[e] = (short)tile[q * 8 + e][sp];
        *(short8*)(dst + (size_t)sp * CI + q * 8) = v;
      }
    }
  } else {
    // ---- prep_w: OIHW fp32 -> Wpre, R3-proven layout:
    // sub-tile s=(r*4+cb) occupies s*16KB; chunk c (0..1023): co=c>>2,
    // granule holds ci-group kg=(c&3)^((c>>3)&3): ci = cb*32+kg*8+e, tap r.
    const int u = (blockIdx.x - 1600) * 256 + t;   // 0..36863
    const int rcbmt = u >> 9;          // 0..71 = ((r*4+cb)*2+half)
    const int p     = u & 511;
    const int mt  = rcbmt & 1;
    const int rcb = rcbmt >> 1;        // 0..35
    const int cb  = rcb & 3;
    const int r   = rcb >> 2;          // 0..8
    const int col = p >> 2;            // co_local 0..127
    const int kg  = (p & 3) ^ ((col >> 1) & 3);
    const int co  = mt * 128 + col;
    const int ci0 = cb * 32 + kg * 8;
    short8 v;
#pragma unroll
    for (int e = 0; e < 8; ++e)
      v[e] = (short)f2bf(W[(size_t)co * KTOT + (size_t)(ci0 + e) * 9 + r]);
    *(short8*)(Wp + (size_t)u * 8) = v;
    if (u < 16) {
      short8 z = {0, 0, 0, 0, 0, 0, 0, 0};
      *(short8*)(Wp + WP_USHORTS + u * 8) = z;
    }
  }
}

// ---------------- conv_gemm: 256x256 tile, 8 waves, 4-deep ring, counted vmcnt (T3+T4+T5) ----
// K split into 36 sub-tiles of 32 (one (r,cb) each). Per sub-step: ONE barrier, vmcnt(8),
// stage(s+3) into ring buf, 12 ds_read_b128, 32 MFMA. Loads issued at s land by s+3.
// grid 196 sp-tiles of 256 ; block 512 = 8 waves (2M x 4N), wave tile 128co x 64sp
__global__ __launch_bounds__(512, 2) void conv_gemm(const unsigned short* __restrict__ Xt,
                                                    const unsigned short* __restrict__ Wp,
                                                    const float* __restrict__ bias,
                                                    float* __restrict__ out) {
  __shared__ __align__(1024) char smem[131072];  // ring of 4 x (A 16K | B 16K)
  const int t    = threadIdx.x;
  const int lane = t & 63;
  const int wid  = t >> 6;
  const int wm   = wid >> 2, wn = wid & 3;

  // bijective XCD swizzle for 196 blocks (q=24, r=4)
  const int orig = blockIdx.x;
  const int xcd = orig & 7, idx = orig >> 3;
  const int spt = (xcd < 4 ? xcd * 25 : 100 + (xcd - 4) * 24) + idx;   // 0..195

  // --- staging precompute: thread t covers B rows S0 (half 0) and S1 (half 1)
  const int kgB = (t & 3) ^ ((t >> 3) & 3);
  const int S0 = spt * 256 + (t >> 2);
  const int S1 = S0 + 128;
  const int hw0 = S0 % PLANE, h0 = hw0 / HW_, w0 = hw0 - h0 * HW_;
  const int hw1 = S1 % PLANE, h1 = hw1 / HW_, w1 = hw1 - h1 * HW_;
  int vm0 = 0, vm1 = 0;
#pragma unroll
  for (int r = 0; r < 9; ++r) {
    int dh = r / 3 - 1, dw = r % 3 - 1;
    vm0 |= (int)(((unsigned)(h0 + dh) < HW_) & ((unsigned)(w0 + dw) < HW_)) << r;
    vm1 |= (int)(((unsigned)(h1 + dh) < HW_) & ((unsigned)(w1 + dw) < HW_)) << r;
  }
  const char* xb0 = (const char*)Xt + ((size_t)S0 * CI + kgB * 8) * 2;
  const char* xb1 = (const char*)Xt + ((size_t)S1 * CI + kgB * 8) * 2;
  const char* zb  = (const char*)(Wp + WP_USHORTS) + (t & 3) * 16;
  const char* wpA = (const char*)Wp + t * 16;

  // fragment read offsets (64B rows, granule swizzle q^((row>>1)&3), lane-constant)
  const int swz  = ((lane >> 4) ^ ((lane >> 1) & 3)) * 16;
  const int aoff = (wm * 128 + (lane & 15)) * 64 + swz;           // + m*1024
  const int boff = 16384 + (wn * 64 + (lane & 15)) * 64 + swz;    // + n*1024

  f32x4 acc[8][4];
  const f32x4 zf = {0.f, 0.f, 0.f, 0.f};
#pragma unroll
  for (int m = 0; m < 8; ++m)
#pragma unroll
    for (int n = 0; n < 4; ++n) acc[m][n] = zf;

  auto SA = [&](int s1, int j, char* buf) {
    gload16(buf + j * 8192 + wid * 1024, wpA + (size_t)s1 * 16384 + j * 8192);
  };
  auto SB = [&](int s1, int j, char* buf) {
    const int r = s1 >> 2, cb = s1 & 3;
    const int dh = r / 3 - 1, dw = r % 3 - 1;
    const int ro = dh * HW_ + dw;
    const bool v = ((j ? vm1 : vm0) >> r) & 1;
    const char* src = (j ? xb1 : xb0) + ro * 256 + cb * 64;
    gload16(buf + 16384 + j * 8192 + wid * 1024, v ? src : zb);
  };
  auto STAGE = [&](int s1) {
    char* nb = smem + (s1 & 3) * 32768;
    SA(s1, 0, nb); SA(s1, 1, nb); SB(s1, 0, nb); SB(s1, 1, nb);
  };

  // prologue: 3 sub-tiles in flight
  STAGE(0); STAGE(1); STAGE(2);

#pragma unroll
  for (int s = 0; s < 36; ++s) {
    // counted wait: sub-tile s's 4 loads (oldest) landed; 8 stay in flight. Never 0 mid-loop.
    if (s <= 33)      vmwait<8>();
    else if (s == 34) vmwait<4>();
    else              vmwait<0>();
    __builtin_amdgcn_s_barrier();      // stage-s data visible to all; all waves past s-1 reads

    if (s <= 32) STAGE(s + 3);         // overwrite buf last read at s-1 (safe post-barrier)

    const char* rb = smem + (s & 3) * 32768;
    short8 aF[8], bF[4];
#pragma unroll
    for (int m = 0; m < 8; ++m) aF[m] = *(const short8*)(rb + aoff + m * 1024);
#pragma unroll
    for (int n = 0; n < 4; ++n) bF[n] = *(const short8*)(rb + boff + n * 1024);

    __builtin_amdgcn_s_setprio(1);
#pragma unroll
    for (int m = 0; m < 8; ++m)
#pragma unroll
      for (int n = 0; n < 4; ++n)
        acc[m][n] = __builtin_amdgcn_mfma_f32_16x16x32_bf16(aF[m], bF[n], acc[m][n], 0, 0, 0);
    __builtin_amdgcn_s_setprio(0);
  }

  // ---- epilogue: D row = co = (lane>>4)*4+reg, col = sp = lane&15
#pragma unroll
  for (int nf = 0; nf < 4; ++nf) {
    int S = spt * 256 + wn * 64 + nf * 16 + (lane & 15);
    int nimg = S / PLANE, hw = S - nimg * PLANE;
    float* ob = out + (size_t)nimg * OUTN + hw;
#pragma unroll
    for (int mf = 0; mf < 8; ++mf) {
      int cob = wm * 128 + mf * 16 + (lane >> 4) * 4;
#pragma unroll
      for (int r2 = 0; r2 < 4; ++r2)
        ob[(size_t)(cob + r2) * PLANE] = acc[mf][nf][r2] + bias[cob + r2];
    }
  }
}

// ---------------- fallback: naive direct conv (only if ws too small) ----------------
__global__ __launch_bounds__(256) void conv_naive(const float* __restrict__ X,
                                                  const float* __restrict__ W,
                                                  const float* __restrict__ bias,
                                                  float* __restrict__ out) {
  int idx = blockIdx.x * 256 + threadIdx.x;
  int hw = idx % PLANE;
  int co = (idx / PLANE) & 255;
  int n  = idx / (PLANE * 256);
  int h = hw / HW_, w = hw - h * HW_;
  float acc = bias[co];
  const float* xp = X + (size_t)n * CI * PLANE;
  const float* wp = W + (size_t)co * KTOT;
  for (int ci = 0; ci < CI; ++ci) {
#pragma unroll
    for (int kh = 0; kh < 3; ++kh) {
      int y = h + kh - 1;
      if ((unsigned)y >= HW_) continue;
#pragma unroll
      for (int kw = 0; kw < 3; ++kw) {
        int x = w + kw - 1;
        if ((unsigned)x >= HW_) continue;
        acc += xp[(size_t)ci * PLANE + y * HW_ + x] * wp[ci * 9 + kh * 3 + kw];
      }
    }
  }
  out[idx] = acc;
}

extern "C" void kernel_launch(void* const* d_in, const int* in_sizes, int n_in,
                              void* d_out, int out_size, void* d_ws, size_t ws_size,
                              hipStream_t stream) {
  (void)in_sizes; (void)n_in; (void)out_size;
  const float* X = (const float*)d_in[0];
  const float* W = (const float*)d_in[1];
  const float* b = (const float*)d_in[2];
  float* out = (float*)d_out;
  if (ws_size >= WS_NEED) {
    unsigned short* Xt = (unsigned short*)d_ws;
    unsigned short* Wp = (unsigned short*)((char*)d_ws + XT_BYTES);
    prep_fused<<<1744, 256, 0, stream>>>(X, W, Xt, Wp);
    conv_gemm<<<196, 512, 0, stream>>>(Xt, Wp, b, out);
  } else {
    conv_naive<<<(NB * CO_ * PLANE + 255) / 256, 256, 0, stream>>>(X, W, b, out);
  }
}